// Round 1
// baseline (15029.715 us; speedup 1.0000x reference)
//
#include <hip/hip_runtime.h>
#include <cstddef>

#define T_STEPS 1024
#define BATCH   64
#define DIN     128
#define HID     256
#define G4      1024   // 4*HID
#define KTOT    384    // DIN+HID

// ws layout (floats):
//   Wr:    [2][384][1024]   off 0       size 786432   (reordered concat weights, row jj4=j*4+q)
//   bias:  [2][1024]        off 786432  size 2048     (bih+bhh, reordered)
//   h_buf: [2][2][64][256]  off 788480  size 65536    ([parity][dir][b][j])
//   c_buf: [2][2][64][256]  off 854016  size 65536
#define WS_WR    0
#define WS_BIAS  786432
#define WS_HBUF  788480
#define WS_CBUF  854016
#define STATE_SZ 32768   // one parity slice: 2*64*256

__global__ void prep_kernel(const float* __restrict__ Wih_f, const float* __restrict__ Whh_f,
                            const float* __restrict__ bih_f, const float* __restrict__ bhh_f,
                            const float* __restrict__ Wih_r, const float* __restrict__ Whh_r,
                            const float* __restrict__ bih_r, const float* __restrict__ bhh_r,
                            const float* __restrict__ hx, const float* __restrict__ cx,
                            float* __restrict__ ws) {
  float* Wr   = ws + WS_WR;
  float* bias = ws + WS_BIAS;
  float* hb   = ws + WS_HBUF;
  float* cb   = ws + WS_CBUF;
  const int total = 786432 + 2048 + STATE_SZ + STATE_SZ;
  for (int i = blockIdx.x * blockDim.x + threadIdx.x; i < total;
       i += gridDim.x * blockDim.x) {
    if (i < 786432) {
      int d   = i / (KTOT * G4);
      int r   = i - d * (KTOT * G4);
      int k   = r >> 10;        // /1024
      int jj4 = r & 1023;
      int j = jj4 >> 2, q = jj4 & 3;
      int g = q * HID + j;
      const float* Wih = d ? Wih_r : Wih_f;
      const float* Whh = d ? Whh_r : Whh_f;
      Wr[i] = (k < DIN) ? Wih[g * DIN + k] : Whh[g * HID + (k - DIN)];
    } else if (i < 786432 + 2048) {
      int r = i - 786432;
      int d = r >> 10;
      int jj4 = r & 1023;
      int j = jj4 >> 2, q = jj4 & 3;
      int g = q * HID + j;
      bias[r] = d ? (bih_r[g] + bhh_r[g]) : (bih_f[g] + bhh_f[g]);
    } else if (i < 786432 + 2048 + STATE_SZ) {
      int r = i - (786432 + 2048);
      hb[r] = hx[r];    // parity 0 slice == hx layout [2][64][256]
    } else {
      int r = i - (786432 + 2048 + STATE_SZ);
      cb[r] = cx[r];
    }
  }
}

// One timestep, both directions. Grid = 256 WGs x 256 threads.
// WG -> (d, jt, bt): d = wg>>7, jt = (wg&127)>>3, bt = wg&7.
// WG computes gate rows jj4 in [jt*64, jt*64+64) for batch rows [bt*8, bt*8+8).
__global__ __launch_bounds__(256) void step_kernel(
    const float* __restrict__ x,     // [1024][64][128]
    const float* __restrict__ Wr,    // [2][384][1024]
    const float* __restrict__ bias,  // [2][1024]
    float* __restrict__ hb,          // [2][2][64][256]
    float* __restrict__ cb,
    float* __restrict__ out,         // [1024][64][512] (+ tail written elsewhere)
    int s) {
  __shared__ float inT[KTOT][9];   // [k][bb] transposed in_vec, pad->conflict-free
  __shared__ float gl[64][9];      // gates [local gate row][bb]

  const int wg  = blockIdx.x;
  const int d   = wg >> 7;
  const int rem = wg & 127;
  const int jt  = rem >> 3;
  const int bt  = rem & 7;
  const int j0  = jt * 16;
  const int b0  = bt * 8;
  const int t   = d ? (T_STEPS - 1 - s) : s;
  const int pr  = s & 1, pw = pr ^ 1;

  // stage [x_t | h_prev] for 8 batch rows, transposed
  const float* hsrc = hb + (size_t)(pr * 2 + d) * BATCH * HID;
  for (int i = threadIdx.x; i < 8 * KTOT; i += 256) {
    int bb = i / KTOT;
    int k  = i - bb * KTOT;
    float v = (k < DIN) ? x[((size_t)t * BATCH + (b0 + bb)) * DIN + k]
                        : hsrc[(size_t)(b0 + bb) * HID + (k - DIN)];
    inT[k][bb] = v;
  }
  __syncthreads();

  const int lane = threadIdx.x & 63;          // local gate row
  const int bb0  = (threadIdx.x >> 6) << 1;   // wave -> batch pair {0,2,4,6}
  const float* Wp = Wr + (size_t)d * KTOT * G4 + (j0 * 4 + lane);
  float a0 = 0.f, a1 = 0.f;
#pragma unroll 8
  for (int k = 0; k < KTOT; ++k) {
    float w = Wp[(size_t)k * G4];
    a0 = fmaf(w, inT[k][bb0], a0);
    a1 = fmaf(w, inT[k][bb0 + 1], a1);
  }
  float bs = bias[d * G4 + j0 * 4 + lane];
  gl[lane][bb0]     = a0 + bs;
  gl[lane][bb0 + 1] = a1 + bs;
  __syncthreads();

  // elementwise: 16 j x 8 b = 128 outputs
  if (threadIdx.x < 128) {
    int jl = threadIdx.x >> 3, bb = threadIdx.x & 7;
    float gi = gl[jl * 4 + 0][bb];
    float gf = gl[jl * 4 + 1][bb];
    float gg = gl[jl * 4 + 2][bb];
    float go = gl[jl * 4 + 3][bb];
    float ii = 1.f / (1.f + expf(-gi));
    float ff = 1.f / (1.f + expf(-gf));
    float g2 = tanhf(gg);
    float oo = 1.f / (1.f + expf(-go));
    int b = b0 + bb, j = j0 + jl;
    size_t cidx = ((size_t)d * BATCH + b) * HID + j;
    float c = ff * cb[(size_t)pr * STATE_SZ + cidx] + ii * g2;
    float h = oo * tanhf(c);
    cb[(size_t)pw * STATE_SZ + cidx] = c;
    hb[(size_t)pw * STATE_SZ + cidx] = h;
    out[((size_t)t * BATCH + b) * (2 * HID) + d * HID + j] = h;
  }
}

__global__ void fin_kernel(const float* __restrict__ hb, const float* __restrict__ cb,
                           float* __restrict__ out) {
  int i = blockIdx.x * blockDim.x + threadIdx.x;
  if (i < STATE_SZ) {
    // final state lives at parity 0 (after 1024 steps)
    out[(size_t)T_STEPS * BATCH * 2 * HID + i] = hb[i];
    out[(size_t)T_STEPS * BATCH * 2 * HID + STATE_SZ + i] = cb[i];
  }
}

extern "C" void kernel_launch(void* const* d_in, const int* in_sizes, int n_in,
                              void* d_out, int out_size, void* d_ws, size_t ws_size,
                              hipStream_t stream) {
  const float* x     = (const float*)d_in[0];
  const float* hx    = (const float*)d_in[1];
  const float* cx    = (const float*)d_in[2];
  const float* Wih_f = (const float*)d_in[3];
  const float* Whh_f = (const float*)d_in[4];
  const float* bih_f = (const float*)d_in[5];
  const float* bhh_f = (const float*)d_in[6];
  const float* Wih_r = (const float*)d_in[7];
  const float* Whh_r = (const float*)d_in[8];
  const float* bih_r = (const float*)d_in[9];
  const float* bhh_r = (const float*)d_in[10];
  float* out = (float*)d_out;
  float* ws  = (float*)d_ws;

  hipLaunchKernelGGL(prep_kernel, dim3(1024), dim3(256), 0, stream,
                     Wih_f, Whh_f, bih_f, bhh_f, Wih_r, Whh_r, bih_r, bhh_r,
                     hx, cx, ws);

  float* Wr   = ws + WS_WR;
  float* bias = ws + WS_BIAS;
  float* hb   = ws + WS_HBUF;
  float* cb   = ws + WS_CBUF;
  for (int s = 0; s < T_STEPS; ++s) {
    hipLaunchKernelGGL(step_kernel, dim3(256), dim3(256), 0, stream,
                       x, Wr, bias, hb, cb, out, s);
  }
  hipLaunchKernelGGL(fin_kernel, dim3(128), dim3(256), 0, stream, hb, cb, out);
}